// Round 3
// baseline (756.172 us; speedup 1.0000x reference)
//
#include <hip/hip_runtime.h>
#include <hip/hip_bf16.h>

#define NN 100000
#define FIN 512
#define H1D 64
#define H2D 128
#define CD 40
#define GP 64           // g3 padded row (bf16) -> one 128B line
#define BNEPS 1e-5f

#define BSHIFT 9
#define BSZ 512
#define NB 196          // ceil(NN / 512)
#define CHUNK 8192      // edges per scatter block

typedef __attribute__((ext_vector_type(8))) short bf16x8;
typedef __attribute__((ext_vector_type(4))) float f32x4;

__device__ __forceinline__ float bf2f(ushort u) {
    union { uint i; float f; } v; v.i = ((uint)u) << 16; return v.f;
}
__device__ __forceinline__ ushort f2bf(float f) {
    union { float f; uint i; } v; v.f = f;
    uint x = v.i;
    return (ushort)((x + 0x7fffu + ((x >> 16) & 1u)) >> 16);
}

// unpack 8 bf16 (one 16B row chunk) and accumulate into a[0..7]
__device__ __forceinline__ void acc8(float* a, uint4 v) {
    a[0] += bf2f((ushort)(v.x & 0xffff)); a[1] += bf2f((ushort)(v.x >> 16));
    a[2] += bf2f((ushort)(v.y & 0xffff)); a[3] += bf2f((ushort)(v.y >> 16));
    a[4] += bf2f((ushort)(v.z & 0xffff)); a[5] += bf2f((ushort)(v.z >> 16));
    a[6] += bf2f((ushort)(v.w & 0xffff)); a[7] += bf2f((ushort)(v.w >> 16));
}

__device__ __forceinline__ uint4 selz(bool q, uint4 v) {
    return q ? v : make_uint4(0u, 0u, 0u, 0u);
}

// ---------------- graph preprocessing: bucketed CSR build ----------------

__global__ __launch_bounds__(256) void bhist_k(const int* __restrict__ dst, int E,
                                               int* __restrict__ bcount) {
    __shared__ int h[NB];
    for (int i = threadIdx.x; i < NB; i += 256) h[i] = 0;
    __syncthreads();
    int i = blockIdx.x * blockDim.x + threadIdx.x;
    int st = gridDim.x * blockDim.x;
    for (; i < E; i += st) atomicAdd(&h[dst[i] >> BSHIFT], 1);
    __syncthreads();
    for (int j = threadIdx.x; j < NB; j += 256)
        if (h[j]) atomicAdd(&bcount[j], h[j]);
}

__global__ __launch_bounds__(256) void bscan_k(const int* __restrict__ bcount,
                                               int* __restrict__ bstart,
                                               int* __restrict__ bcursor) {
    __shared__ int sh[NB];
    int tid = threadIdx.x;
    if (tid < NB) sh[tid] = bcount[tid];
    __syncthreads();
    for (int off = 1; off < NB; off <<= 1) {
        int v = (tid < NB && tid >= off) ? sh[tid - off] : 0;
        __syncthreads();
        if (tid < NB) sh[tid] += v;
        __syncthreads();
    }
    if (tid < NB) {
        int s = tid ? sh[tid - 1] : 0;
        bstart[tid] = s;
        bcursor[tid] = s;
    }
    if (tid == 0) bstart[NB] = sh[NB - 1];
}

__global__ __launch_bounds__(256) void bscatter_k(const int* __restrict__ src,
                                                  const int* __restrict__ dst, int E,
                                                  int* __restrict__ bcursor,
                                                  int* __restrict__ ebuf) {
    __shared__ int hist[NB];
    __shared__ int loff[NB];
    __shared__ int lcur[NB];
    __shared__ int gbase[NB];
    __shared__ int sbuf[CHUNK];
    int tid = threadIdx.x;
    int e0 = blockIdx.x * CHUNK;
    int e1 = e0 + CHUNK; if (e1 > E) e1 = E;

    for (int i = tid; i < NB; i += 256) hist[i] = 0;
    __syncthreads();
    for (int i = e0 + tid; i < e1; i += 256) atomicAdd(&hist[dst[i] >> BSHIFT], 1);
    __syncthreads();
    int v = (tid < NB) ? hist[tid] : 0;
    __syncthreads();
    if (tid < NB) loff[tid] = v;
    __syncthreads();
    for (int off = 1; off < NB; off <<= 1) {
        int u = (tid < NB && tid >= off) ? loff[tid - off] : 0;
        __syncthreads();
        if (tid < NB) loff[tid] += u;
        __syncthreads();
    }
    if (tid < NB) {
        int excl = loff[tid] - v;
        loff[tid] = excl;
        lcur[tid] = excl;
        gbase[tid] = (v > 0) ? atomicAdd(&bcursor[tid], v) : 0;
    }
    __syncthreads();
    for (int i = e0 + tid; i < e1; i += 256) {
        int d = dst[i];
        int b = d >> BSHIFT;
        int pos = atomicAdd(&lcur[b], 1);
        sbuf[pos] = (src[i] << BSHIFT) | (d & (BSZ - 1));
    }
    __syncthreads();
    int wave = tid >> 6, lane = tid & 63;
    for (int b = wave; b < NB; b += 4) {
        int cnt = (b + 1 < NB ? loff[b + 1] : (e1 - e0)) - loff[b];
        int s0 = loff[b], d0 = gbase[b];
        for (int k = lane; k < cnt; k += 64) ebuf[d0 + k] = sbuf[s0 + k];
    }
}

__global__ __launch_bounds__(256) void bcsr_k(const int* __restrict__ ebuf,
                                              const int* __restrict__ bstart,
                                              int* __restrict__ rowstart,
                                              float* __restrict__ dinv,
                                              int* __restrict__ csr, int E) {
    __shared__ int ldeg[BSZ];
    __shared__ int lcur[BSZ];
    __shared__ int s2[256];
    int b = blockIdx.x, tid = threadIdx.x;
    int node0 = b << BSHIFT;
    int es = bstart[b], ee = bstart[b + 1];
    ldeg[tid] = 0; ldeg[tid + 256] = 0;
    __syncthreads();
    for (int i = es + tid; i < ee; i += 256) atomicAdd(&ldeg[ebuf[i] & (BSZ - 1)], 1);
    __syncthreads();
    int a0 = ldeg[2 * tid], a1 = ldeg[2 * tid + 1];
    s2[tid] = a0 + a1;
    __syncthreads();
    for (int off = 1; off < 256; off <<= 1) {
        int u = (tid >= off) ? s2[tid - off] : 0;
        __syncthreads();
        s2[tid] += u;
        __syncthreads();
    }
    int base2 = tid ? s2[tid - 1] : 0;
    int ex0 = base2, ex1 = base2 + a0;
    int n0 = node0 + 2 * tid, n1 = n0 + 1;
    if (n0 < NN) { rowstart[n0] = es + ex0; dinv[n0] = rsqrtf((float)(a0 + 1)); }
    if (n1 < NN) { rowstart[n1] = es + ex1; dinv[n1] = rsqrtf((float)(a1 + 1)); }
    lcur[2 * tid] = es + ex0;
    lcur[2 * tid + 1] = es + ex1;
    __syncthreads();
    for (int i = es + tid; i < ee; i += 256) {
        int e = ebuf[i];
        int pos = atomicAdd(&lcur[e & (BSZ - 1)], 1);
        csr[pos] = ((unsigned)e) >> BSHIFT;
    }
    if (b == 0 && tid == 0) rowstart[NN] = E;
}

// ---------------- W1 -> bf16 transposed [64][512] ----------------
__global__ __launch_bounds__(256) void w1cvt_k(const float* __restrict__ W1,
                                               ushort* __restrict__ w1t) {
    int i = blockIdx.x * 256 + threadIdx.x;
    if (i < FIN * H1D) {
        int n = i >> 9, k = i & 511;
        w1t[i] = f2bf(W1[k * H1D + n]);
    }
}

// ---------------- GEMM1 (MFMA bf16): t1 = bf16( (x @ W1) * dinv ) ----------------
// block = 512 (8 waves, 128 rows), one shared 66.5KB B-stage -> 2 blocks/CU =
// 16 waves/CU = 4 waves/SIMD (vs 2 before): doubles HBM latency hiding.
#define BPAD 520
__global__ __launch_bounds__(512) void gemm1_k(const float* __restrict__ x,
                                               const ushort* __restrict__ w1t,
                                               const float* __restrict__ dinv,
                                               ushort* __restrict__ t1) {
    __shared__ ushort sB[H1D * BPAD];   // 66.5 KB, row pad -> 2-way max conflicts
    int tid = threadIdx.x;
    {
        int row = tid >> 3, seg = tid & 7;   // 64 rows x 8 segs x 64 ushorts
        const uint4* srcp = (const uint4*)(w1t + row * FIN + seg * 64);
        uint4* dstp = (uint4*)(sB + row * BPAD + seg * 64);
#pragma unroll
        for (int j = 0; j < 8; ++j) dstp[j] = srcp[j];
    }
    __syncthreads();
    int wave = tid >> 6, lane = tid & 63;
    int lm = lane & 15, q = lane >> 4;
    int r0 = blockIdx.x * 128 + wave * 16;
    int mrow = r0 + lm;
    int mc = mrow < NN ? mrow : NN - 1;
    const float* ap = x + (size_t)mc * FIN + q * 8;
    const ushort* bp = sB + (size_t)lm * BPAD + q * 8;
    f32x4 acc0 = {0.f, 0.f, 0.f, 0.f}, acc1 = acc0, acc2 = acc0, acc3 = acc0;
#pragma unroll 4
    for (int kb = 0; kb < FIN; kb += 32) {
        f32x4 a01 = __builtin_nontemporal_load((const f32x4*)(ap + kb));
        f32x4 a23 = __builtin_nontemporal_load((const f32x4*)(ap + kb + 4));
        union { bf16x8 v8; __hip_bfloat162 h2[4]; } ua;
        ua.h2[0] = __float22bfloat162_rn(make_float2(a01[0], a01[1]));
        ua.h2[1] = __float22bfloat162_rn(make_float2(a01[2], a01[3]));
        ua.h2[2] = __float22bfloat162_rn(make_float2(a23[0], a23[1]));
        ua.h2[3] = __float22bfloat162_rn(make_float2(a23[2], a23[3]));
        bf16x8 b0 = *(const bf16x8*)(bp + kb);
        bf16x8 b1 = *(const bf16x8*)(bp + 16 * BPAD + kb);
        bf16x8 b2 = *(const bf16x8*)(bp + 32 * BPAD + kb);
        bf16x8 b3 = *(const bf16x8*)(bp + 48 * BPAD + kb);
        acc0 = __builtin_amdgcn_mfma_f32_16x16x32_bf16(ua.v8, b0, acc0, 0, 0, 0);
        acc1 = __builtin_amdgcn_mfma_f32_16x16x32_bf16(ua.v8, b1, acc1, 0, 0, 0);
        acc2 = __builtin_amdgcn_mfma_f32_16x16x32_bf16(ua.v8, b2, acc2, 0, 0, 0);
        acc3 = __builtin_amdgcn_mfma_f32_16x16x32_bf16(ua.v8, b3, acc3, 0, 0, 0);
    }
    // C/D: col = lane&15 (within 16-col block), row = q*4 + reg
    int rbase = r0 + q * 4;
#pragma unroll
    for (int r = 0; r < 4; ++r) {
        int row = rbase + r;
        if (row < NN) {
            float dv = dinv[row];
            ushort* o = t1 + (size_t)row * H1D;
            o[lm]      = f2bf(acc0[r] * dv);
            o[16 + lm] = f2bf(acc1[r] * dv);
            o[32 + lm] = f2bf(acc2[r] * dv);
            o[48 + lm] = f2bf(acc3[r] * dv);
        }
    }
}

// ---------------- aggregation over 64-dim bf16 rows, TWO nodes per wave ----------------
// (layer-1 only now; layer-2 aggregation is fused into aggp_k below)
// MODE 1: out = relu((dinv*sum)*sc + sv) * dinv
template <int MODE>
__global__ __launch_bounds__(256) void agg64_k(const ushort* __restrict__ tin,
                                               ushort* __restrict__ tout,
                                               const int* __restrict__ rowstart,
                                               const int* __restrict__ csr,
                                               const float* __restrict__ dinv,
                                               const float* __restrict__ g,
                                               const float* __restrict__ bt,
                                               const float* __restrict__ rm,
                                               const float* __restrict__ rv,
                                               const float* __restrict__ b,
                                               int E) {
    int w = (blockIdx.x * blockDim.x + threadIdx.x) >> 6;
    int lane = threadIdx.x & 63;
    int nA = 2 * w;
    if (nA >= NN) return;
    int nB = nA + 1;                 // NN even -> always valid
    int gsl = lane >> 3, c = lane & 7;
    int base = 8 * c;
    int2 r01 = *(const int2*)(rowstart + nA);
    int reB = rowstart[nA + 2];
    int iA = r01.x, reA = r01.y;
    int iB = reA;
    int Em1 = E - 1;
    float a[8], y[8];
#pragma unroll
    for (int j = 0; j < 8; ++j) { a[j] = 0.f; y[j] = 0.f; }

    for (;;) {
        bool dA = (iA + 32 <= reA);
        bool dB = (iB + 32 <= reB);
        if (!(dA | dB)) break;
        int jA0 = dA ? iA + gsl      : Em1;
        int jA1 = dA ? iA + 8 + gsl  : Em1;
        int jA2 = dA ? iA + 16 + gsl : Em1;
        int jA3 = dA ? iA + 24 + gsl : Em1;
        int jB0 = dB ? iB + gsl      : Em1;
        int jB1 = dB ? iB + 8 + gsl  : Em1;
        int jB2 = dB ? iB + 16 + gsl : Em1;
        int jB3 = dB ? iB + 24 + gsl : Em1;
        int sA0 = csr[jA0], sA1 = csr[jA1], sA2 = csr[jA2], sA3 = csr[jA3];
        int sB0 = csr[jB0], sB1 = csr[jB1], sB2 = csr[jB2], sB3 = csr[jB3];
        uint4 vA0 = *(const uint4*)(tin + (size_t)sA0 * H1D + base);
        uint4 vA1 = *(const uint4*)(tin + (size_t)sA1 * H1D + base);
        uint4 vA2 = *(const uint4*)(tin + (size_t)sA2 * H1D + base);
        uint4 vA3 = *(const uint4*)(tin + (size_t)sA3 * H1D + base);
        uint4 vB0 = *(const uint4*)(tin + (size_t)sB0 * H1D + base);
        uint4 vB1 = *(const uint4*)(tin + (size_t)sB1 * H1D + base);
        uint4 vB2 = *(const uint4*)(tin + (size_t)sB2 * H1D + base);
        uint4 vB3 = *(const uint4*)(tin + (size_t)sB3 * H1D + base);
        vA0 = selz(dA, vA0); vA1 = selz(dA, vA1); vA2 = selz(dA, vA2); vA3 = selz(dA, vA3);
        vB0 = selz(dB, vB0); vB1 = selz(dB, vB1); vB2 = selz(dB, vB2); vB3 = selz(dB, vB3);
        acc8(a, vA0); acc8(a, vA1); acc8(a, vA2); acc8(a, vA3);
        acc8(y, vB0); acc8(y, vB1); acc8(y, vB2); acc8(y, vB3);
        iA += dA ? 32 : 0;
        iB += dB ? 32 : 0;
    }
    // masked remainder batch (<=31 edges per node), 8 gathers in flight
    {
        bool qA0 = iA + gsl < reA,      qB0 = iB + gsl < reB;
        bool qA1 = iA + 8 + gsl < reA,  qB1 = iB + 8 + gsl < reB;
        bool qA2 = iA + 16 + gsl < reA, qB2 = iB + 16 + gsl < reB;
        bool qA3 = iA + 24 + gsl < reA, qB3 = iB + 24 + gsl < reB;
        int jA0 = qA0 ? iA + gsl      : Em1;
        int jA1 = qA1 ? iA + 8 + gsl  : Em1;
        int jA2 = qA2 ? iA + 16 + gsl : Em1;
        int jA3 = qA3 ? iA + 24 + gsl : Em1;
        int jB0 = qB0 ? iB + gsl      : Em1;
        int jB1 = qB1 ? iB + 8 + gsl  : Em1;
        int jB2 = qB2 ? iB + 16 + gsl : Em1;
        int jB3 = qB3 ? iB + 24 + gsl : Em1;
        int sA0 = csr[jA0], sA1 = csr[jA1], sA2 = csr[jA2], sA3 = csr[jA3];
        int sB0 = csr[jB0], sB1 = csr[jB1], sB2 = csr[jB2], sB3 = csr[jB3];
        uint4 vA0 = *(const uint4*)(tin + (size_t)sA0 * H1D + base);
        uint4 vA1 = *(const uint4*)(tin + (size_t)sA1 * H1D + base);
        uint4 vA2 = *(const uint4*)(tin + (size_t)sA2 * H1D + base);
        uint4 vA3 = *(const uint4*)(tin + (size_t)sA3 * H1D + base);
        uint4 vB0 = *(const uint4*)(tin + (size_t)sB0 * H1D + base);
        uint4 vB1 = *(const uint4*)(tin + (size_t)sB1 * H1D + base);
        uint4 vB2 = *(const uint4*)(tin + (size_t)sB2 * H1D + base);
        uint4 vB3 = *(const uint4*)(tin + (size_t)sB3 * H1D + base);
        vA0 = selz(qA0, vA0); vA1 = selz(qA1, vA1); vA2 = selz(qA2, vA2); vA3 = selz(qA3, vA3);
        vB0 = selz(qB0, vB0); vB1 = selz(qB1, vB1); vB2 = selz(qB2, vB2); vB3 = selz(qB3, vB3);
        acc8(a, vA0); acc8(a, vA1); acc8(a, vA2); acc8(a, vA3);
        acc8(y, vB0); acc8(y, vB1); acc8(y, vB2); acc8(y, vB3);
    }
    // self rows
    uint4 svA = *(const uint4*)(tin + (size_t)nA * H1D + base);
    uint4 svB = *(const uint4*)(tin + (size_t)nB * H1D + base);
#pragma unroll
    for (int j = 0; j < 8; ++j) a[j] += __shfl_xor(a[j], 8);
#pragma unroll
    for (int j = 0; j < 8; ++j) a[j] += __shfl_xor(a[j], 16);
#pragma unroll
    for (int j = 0; j < 8; ++j) a[j] += __shfl_xor(a[j], 32);
#pragma unroll
    for (int j = 0; j < 8; ++j) y[j] += __shfl_xor(y[j], 8);
#pragma unroll
    for (int j = 0; j < 8; ++j) y[j] += __shfl_xor(y[j], 16);
#pragma unroll
    for (int j = 0; j < 8; ++j) y[j] += __shfl_xor(y[j], 32);
    acc8(a, svA);
    acc8(y, svB);
    float2 dv2 = *(const float2*)(dinv + nA);
    float dv = (gsl == 0) ? dv2.x : dv2.y;
    float s[8];
#pragma unroll
    for (int j = 0; j < 8; ++j) s[j] = (gsl == 0) ? a[j] : y[j];
    float z[8];
    if (MODE == 1) {
        int f0 = base;
        float4 G0 = *(const float4*)(g + f0),  G1 = *(const float4*)(g + f0 + 4);
        float4 V0 = *(const float4*)(rv + f0), V1 = *(const float4*)(rv + f0 + 4);
        float4 B0 = *(const float4*)(b + f0),  B1 = *(const float4*)(b + f0 + 4);
        float4 M0 = *(const float4*)(rm + f0), M1 = *(const float4*)(rm + f0 + 4);
        float4 T0 = *(const float4*)(bt + f0), T1 = *(const float4*)(bt + f0 + 4);
        float sc[8] = { G0.x * rsqrtf(V0.x + BNEPS), G0.y * rsqrtf(V0.y + BNEPS),
                        G0.z * rsqrtf(V0.z + BNEPS), G0.w * rsqrtf(V0.w + BNEPS),
                        G1.x * rsqrtf(V1.x + BNEPS), G1.y * rsqrtf(V1.y + BNEPS),
                        G1.z * rsqrtf(V1.z + BNEPS), G1.w * rsqrtf(V1.w + BNEPS) };
        float sh[8] = { (B0.x - M0.x) * sc[0] + T0.x, (B0.y - M0.y) * sc[1] + T0.y,
                        (B0.z - M0.z) * sc[2] + T0.z, (B0.w - M0.w) * sc[3] + T0.w,
                        (B1.x - M1.x) * sc[4] + T1.x, (B1.y - M1.y) * sc[5] + T1.y,
                        (B1.z - M1.z) * sc[6] + T1.z, (B1.w - M1.w) * sc[7] + T1.w };
#pragma unroll
        for (int j = 0; j < 8; ++j)
            z[j] = fmaxf(s[j] * dv * sc[j] + sh[j], 0.f) * dv;
    } else {
#pragma unroll
        for (int j = 0; j < 8; ++j) z[j] = s[j] * dv;
    }
    if (gsl < 2) {
        uint4 o;
        o.x = (uint)f2bf(z[0]) | ((uint)f2bf(z[1]) << 16);
        o.y = (uint)f2bf(z[2]) | ((uint)f2bf(z[3]) << 16);
        o.z = (uint)f2bf(z[4]) | ((uint)f2bf(z[5]) << 16);
        o.w = (uint)f2bf(z[6]) | ((uint)f2bf(z[7]) << 16);
        *(uint4*)(tout + (size_t)(nA + gsl) * H1D + base) = o;
    }
}

// ---------------- FUSED layer-2 aggregation + GEMM2 + BN2 + ReLU + GEMM3 ----------------
// Gather phase identical to agg64<2> (2 nodes/wave, 8 gathers in flight); the
// GEMM work then runs in the SAME waves (VALU rides under gather latency).
// Kills the u2 write+read (25.6 MB) and one kernel dispatch.
// LDS: W2 packed-bf16 pairs 16KB + W3^T fp32 21.1KB + BN 1KB + u 2KB + h 4KB
//  = 44.2KB -> 3 blocks/CU (12 waves/CU).
#define APB 8   // nodes per block = 4 waves x 2
__global__ __launch_bounds__(256) void aggp_k(const ushort* __restrict__ tin,
                                              const float* __restrict__ W2,
                                              const float* __restrict__ b2,
                                              const float* __restrict__ W3,
                                              const float* __restrict__ g2,
                                              const float* __restrict__ bt2,
                                              const float* __restrict__ rm2,
                                              const float* __restrict__ rv2,
                                              const int* __restrict__ rowstart,
                                              const int* __restrict__ csr,
                                              const float* __restrict__ dinv,
                                              ushort* __restrict__ g3,
                                              int E) {
    __shared__ uint  sW2p[H1D * 64];     // packed bf16 (W2[l][f], W2[l][f+64])
    __shared__ float sW3T[CD][132];      // [o][f], pad 132 -> 16B-aligned rows
    __shared__ float sc2[H2D], sh2[H2D];
    __shared__ float su[APB][H1D];
    __shared__ float sh[APB][H2D];
    int tid = threadIdx.x;
    for (int i = tid; i < H1D * 64; i += 256) {
        int l = i >> 6, fl = i & 63;
        uint pk = (uint)f2bf(W2[l * H2D + fl]) | ((uint)f2bf(W2[l * H2D + 64 + fl]) << 16);
        sW2p[i] = pk;
    }
    for (int i = tid; i < H2D * CD; i += 256) {
        int f = i / CD, o = i - f * CD;
        sW3T[o][f] = W3[i];
    }
    if (tid < H2D) {
        float s = g2[tid] * rsqrtf(rv2[tid] + BNEPS);
        sc2[tid] = s;
        sh2[tid] = (b2[tid] - rm2[tid]) * s + bt2[tid];
    }
    __syncthreads();
    int wave = tid >> 6, lane = tid & 63;
    int nA = blockIdx.x * APB + 2 * wave;     // NN % APB == 0 -> always valid
    if (nA >= NN) return;
    int nB = nA + 1;
    int gsl = lane >> 3, c = lane & 7;
    int base = 8 * c;
    int2 r01 = *(const int2*)(rowstart + nA);
    int reB = rowstart[nA + 2];
    int iA = r01.x, reA = r01.y;
    int iB = reA;
    int Em1 = E - 1;
    float a[8], y[8];
#pragma unroll
    for (int j = 0; j < 8; ++j) { a[j] = 0.f; y[j] = 0.f; }

    for (;;) {
        bool dA = (iA + 32 <= reA);
        bool dB = (iB + 32 <= reB);
        if (!(dA | dB)) break;
        int jA0 = dA ? iA + gsl      : Em1;
        int jA1 = dA ? iA + 8 + gsl  : Em1;
        int jA2 = dA ? iA + 16 + gsl : Em1;
        int jA3 = dA ? iA + 24 + gsl : Em1;
        int jB0 = dB ? iB + gsl      : Em1;
        int jB1 = dB ? iB + 8 + gsl  : Em1;
        int jB2 = dB ? iB + 16 + gsl : Em1;
        int jB3 = dB ? iB + 24 + gsl : Em1;
        int sA0 = csr[jA0], sA1 = csr[jA1], sA2 = csr[jA2], sA3 = csr[jA3];
        int sB0 = csr[jB0], sB1 = csr[jB1], sB2 = csr[jB2], sB3 = csr[jB3];
        uint4 vA0 = *(const uint4*)(tin + (size_t)sA0 * H1D + base);
        uint4 vA1 = *(const uint4*)(tin + (size_t)sA1 * H1D + base);
        uint4 vA2 = *(const uint4*)(tin + (size_t)sA2 * H1D + base);
        uint4 vA3 = *(const uint4*)(tin + (size_t)sA3 * H1D + base);
        uint4 vB0 = *(const uint4*)(tin + (size_t)sB0 * H1D + base);
        uint4 vB1 = *(const uint4*)(tin + (size_t)sB1 * H1D + base);
        uint4 vB2 = *(const uint4*)(tin + (size_t)sB2 * H1D + base);
        uint4 vB3 = *(const uint4*)(tin + (size_t)sB3 * H1D + base);
        vA0 = selz(dA, vA0); vA1 = selz(dA, vA1); vA2 = selz(dA, vA2); vA3 = selz(dA, vA3);
        vB0 = selz(dB, vB0); vB1 = selz(dB, vB1); vB2 = selz(dB, vB2); vB3 = selz(dB, vB3);
        acc8(a, vA0); acc8(a, vA1); acc8(a, vA2); acc8(a, vA3);
        acc8(y, vB0); acc8(y, vB1); acc8(y, vB2); acc8(y, vB3);
        iA += dA ? 32 : 0;
        iB += dB ? 32 : 0;
    }
    {
        bool qA0 = iA + gsl < reA,      qB0 = iB + gsl < reB;
        bool qA1 = iA + 8 + gsl < reA,  qB1 = iB + 8 + gsl < reB;
        bool qA2 = iA + 16 + gsl < reA, qB2 = iB + 16 + gsl < reB;
        bool qA3 = iA + 24 + gsl < reA, qB3 = iB + 24 + gsl < reB;
        int jA0 = qA0 ? iA + gsl      : Em1;
        int jA1 = qA1 ? iA + 8 + gsl  : Em1;
        int jA2 = qA2 ? iA + 16 + gsl : Em1;
        int jA3 = qA3 ? iA + 24 + gsl : Em1;
        int jB0 = qB0 ? iB + gsl      : Em1;
        int jB1 = qB1 ? iB + 8 + gsl  : Em1;
        int jB2 = qB2 ? iB + 16 + gsl : Em1;
        int jB3 = qB3 ? iB + 24 + gsl : Em1;
        int sA0 = csr[jA0], sA1 = csr[jA1], sA2 = csr[jA2], sA3 = csr[jA3];
        int sB0 = csr[jB0], sB1 = csr[jB1], sB2 = csr[jB2], sB3 = csr[jB3];
        uint4 vA0 = *(const uint4*)(tin + (size_t)sA0 * H1D + base);
        uint4 vA1 = *(const uint4*)(tin + (size_t)sA1 * H1D + base);
        uint4 vA2 = *(const uint4*)(tin + (size_t)sA2 * H1D + base);
        uint4 vA3 = *(const uint4*)(tin + (size_t)sA3 * H1D + base);
        uint4 vB0 = *(const uint4*)(tin + (size_t)sB0 * H1D + base);
        uint4 vB1 = *(const uint4*)(tin + (size_t)sB1 * H1D + base);
        uint4 vB2 = *(const uint4*)(tin + (size_t)sB2 * H1D + base);
        uint4 vB3 = *(const uint4*)(tin + (size_t)sB3 * H1D + base);
        vA0 = selz(qA0, vA0); vA1 = selz(qA1, vA1); vA2 = selz(qA2, vA2); vA3 = selz(qA3, vA3);
        vB0 = selz(qB0, vB0); vB1 = selz(qB1, vB1); vB2 = selz(qB2, vB2); vB3 = selz(qB3, vB3);
        acc8(a, vA0); acc8(a, vA1); acc8(a, vA2); acc8(a, vA3);
        acc8(y, vB0); acc8(y, vB1); acc8(y, vB2); acc8(y, vB3);
    }
    uint4 svA = *(const uint4*)(tin + (size_t)nA * H1D + base);
    uint4 svB = *(const uint4*)(tin + (size_t)nB * H1D + base);
#pragma unroll
    for (int j = 0; j < 8; ++j) a[j] += __shfl_xor(a[j], 8);
#pragma unroll
    for (int j = 0; j < 8; ++j) a[j] += __shfl_xor(a[j], 16);
#pragma unroll
    for (int j = 0; j < 8; ++j) a[j] += __shfl_xor(a[j], 32);
#pragma unroll
    for (int j = 0; j < 8; ++j) y[j] += __shfl_xor(y[j], 8);
#pragma unroll
    for (int j = 0; j < 8; ++j) y[j] += __shfl_xor(y[j], 16);
#pragma unroll
    for (int j = 0; j < 8; ++j) y[j] += __shfl_xor(y[j], 32);
    acc8(a, svA);
    acc8(y, svB);
    float2 dv2 = *(const float2*)(dinv + nA);
    // u2 = dinv * sum (fp32, no bf16 round-trip) -> LDS, per-wave private rows
    if (gsl < 2) {
        float dv = (gsl == 0) ? dv2.x : dv2.y;
        int n = 2 * wave + gsl;
        float s0 = (gsl == 0) ? a[0] : y[0], s1 = (gsl == 0) ? a[1] : y[1];
        float s2v = (gsl == 0) ? a[2] : y[2], s3 = (gsl == 0) ? a[3] : y[3];
        float s4 = (gsl == 0) ? a[4] : y[4], s5 = (gsl == 0) ? a[5] : y[5];
        float s6 = (gsl == 0) ? a[6] : y[6], s7 = (gsl == 0) ? a[7] : y[7];
        *(float4*)&su[n][base]     = make_float4(s0 * dv, s1 * dv, s2v * dv, s3 * dv);
        *(float4*)&su[n][base + 4] = make_float4(s4 * dv, s5 * dv, s6 * dv, s7 * dv);
    }
    // intra-wave LDS write->read: no barrier needed, waitcnt ordering suffices
    int n0 = 2 * wave, n1 = n0 + 1;
    // phase2: h[f] = relu(bn2( sum_l u[l]*W2[l][f] )), f = lane and lane+64
    float hA0 = 0.f, hA1 = 0.f, hB0 = 0.f, hB1 = 0.f;
#pragma unroll 4
    for (int l4 = 0; l4 < H1D / 4; ++l4) {
        float4 uA4 = *(const float4*)&su[n0][4 * l4];
        float4 uB4 = *(const float4*)&su[n1][4 * l4];
#pragma unroll
        for (int k = 0; k < 4; ++k) {
            uint w = sW2p[(4 * l4 + k) * 64 + lane];
            float w0 = bf2f((ushort)(w & 0xffff));
            float w1 = bf2f((ushort)(w >> 16));
            float uA = (k == 0) ? uA4.x : (k == 1) ? uA4.y : (k == 2) ? uA4.z : uA4.w;
            float uB = (k == 0) ? uB4.x : (k == 1) ? uB4.y : (k == 2) ? uB4.z : uB4.w;
            hA0 += uA * w0; hA1 += uA * w1;
            hB0 += uB * w0; hB1 += uB * w1;
        }
    }
    {
        float c0 = sc2[lane], c1 = sc2[64 + lane];
        float t0 = sh2[lane], t1v = sh2[64 + lane];
        sh[n0][lane]      = fmaxf(hA0 * c0 + t0, 0.f);
        sh[n0][64 + lane] = fmaxf(hA1 * c1 + t1v, 0.f);
        sh[n1][lane]      = fmaxf(hB0 * c0 + t0, 0.f);
        sh[n1][64 + lane] = fmaxf(hB1 * c1 + t1v, 0.f);
    }
    // phase3: out[o] = sum_f h[f]*W3[f][o], o = lane (<40); then *dinv -> g3
    if (lane < CD) {
        float gA = 0.f, gB = 0.f;
#pragma unroll 4
        for (int f4 = 0; f4 < H2D / 4; ++f4) {
            float4 wv = *(const float4*)&sW3T[lane][4 * f4];
            float4 ha = *(const float4*)&sh[n0][4 * f4];
            float4 hb = *(const float4*)&sh[n1][4 * f4];
            gA += wv.x * ha.x + wv.y * ha.y + wv.z * ha.z + wv.w * ha.w;
            gB += wv.x * hb.x + wv.y * hb.y + wv.z * hb.z + wv.w * hb.w;
        }
        g3[(size_t)nA * GP + lane] = f2bf(gA * dv2.x);
        g3[(size_t)nB * GP + lane] = f2bf(gB * dv2.y);
    }
    // pad cols 40..63: agg40 reads but never uses them numerically -> no zeroing
}

// ---------------- aggregation over padded 40-dim bf16 + bias + log_softmax ----------------
__global__ __launch_bounds__(256) void agg40_k(const ushort* __restrict__ g3,
                                               const float* __restrict__ b3,
                                               const int* __restrict__ rowstart,
                                               const int* __restrict__ csr,
                                               const float* __restrict__ dinv,
                                               float* __restrict__ out,
                                               int E) {
    int w = (blockIdx.x * blockDim.x + threadIdx.x) >> 6;
    int lane = threadIdx.x & 63;
    int nA = 2 * w;
    if (nA >= NN) return;
    int nB = nA + 1;
    int gsl = lane >> 3, c = lane & 7;
    int base = 8 * c;
    int2 r01 = *(const int2*)(rowstart + nA);
    int reB = rowstart[nA + 2];
    int iA = r01.x, reA = r01.y;
    int iB = reA;
    int Em1 = E - 1;
    float a[8], y[8];
#pragma unroll
    for (int j = 0; j < 8; ++j) { a[j] = 0.f; y[j] = 0.f; }

    for (;;) {
        bool dA = (iA + 32 <= reA);
        bool dB = (iB + 32 <= reB);
        if (!(dA | dB)) break;
        int jA0 = dA ? iA + gsl      : Em1;
        int jA1 = dA ? iA + 8 + gsl  : Em1;
        int jA2 = dA ? iA + 16 + gsl : Em1;
        int jA3 = dA ? iA + 24 + gsl : Em1;
        int jB0 = dB ? iB + gsl      : Em1;
        int jB1 = dB ? iB + 8 + gsl  : Em1;
        int jB2 = dB ? iB + 16 + gsl : Em1;
        int jB3 = dB ? iB + 24 + gsl : Em1;
        int sA0 = csr[jA0], sA1 = csr[jA1], sA2 = csr[jA2], sA3 = csr[jA3];
        int sB0 = csr[jB0], sB1 = csr[jB1], sB2 = csr[jB2], sB3 = csr[jB3];
        uint4 vA0 = *(const uint4*)(g3 + (size_t)sA0 * GP + base);
        uint4 vA1 = *(const uint4*)(g3 + (size_t)sA1 * GP + base);
        uint4 vA2 = *(const uint4*)(g3 + (size_t)sA2 * GP + base);
        uint4 vA3 = *(const uint4*)(g3 + (size_t)sA3 * GP + base);
        uint4 vB0 = *(const uint4*)(g3 + (size_t)sB0 * GP + base);
        uint4 vB1 = *(const uint4*)(g3 + (size_t)sB1 * GP + base);
        uint4 vB2 = *(const uint4*)(g3 + (size_t)sB2 * GP + base);
        uint4 vB3 = *(const uint4*)(g3 + (size_t)sB3 * GP + base);
        vA0 = selz(dA, vA0); vA1 = selz(dA, vA1); vA2 = selz(dA, vA2); vA3 = selz(dA, vA3);
        vB0 = selz(dB, vB0); vB1 = selz(dB, vB1); vB2 = selz(dB, vB2); vB3 = selz(dB, vB3);
        acc8(a, vA0); acc8(a, vA1); acc8(a, vA2); acc8(a, vA3);
        acc8(y, vB0); acc8(y, vB1); acc8(y, vB2); acc8(y, vB3);
        iA += dA ? 32 : 0;
        iB += dB ? 32 : 0;
    }
    {
        bool qA0 = iA + gsl < reA,      qB0 = iB + gsl < reB;
        bool qA1 = iA + 8 + gsl < reA,  qB1 = iB + 8 + gsl < reB;
        bool qA2 = iA + 16 + gsl < reA, qB2 = iB + 16 + gsl < reB;
        bool qA3 = iA + 24 + gsl < reA, qB3 = iB + 24 + gsl < reB;
        int jA0 = qA0 ? iA + gsl      : Em1;
        int jA1 = qA1 ? iA + 8 + gsl  : Em1;
        int jA2 = qA2 ? iA + 16 + gsl : Em1;
        int jA3 = qA3 ? iA + 24 + gsl : Em1;
        int jB0 = qB0 ? iB + gsl      : Em1;
        int jB1 = qB1 ? iB + 8 + gsl  : Em1;
        int jB2 = qB2 ? iB + 16 + gsl : Em1;
        int jB3 = qB3 ? iB + 24 + gsl : Em1;
        int sA0 = csr[jA0], sA1 = csr[jA1], sA2 = csr[jA2], sA3 = csr[jA3];
        int sB0 = csr[jB0], sB1 = csr[jB1], sB2 = csr[jB2], sB3 = csr[jB3];
        uint4 vA0 = *(const uint4*)(g3 + (size_t)sA0 * GP + base);
        uint4 vA1 = *(const uint4*)(g3 + (size_t)sA1 * GP + base);
        uint4 vA2 = *(const uint4*)(g3 + (size_t)sA2 * GP + base);
        uint4 vA3 = *(const uint4*)(g3 + (size_t)sA3 * GP + base);
        uint4 vB0 = *(const uint4*)(g3 + (size_t)sB0 * GP + base);
        uint4 vB1 = *(const uint4*)(g3 + (size_t)sB1 * GP + base);
        uint4 vB2 = *(const uint4*)(g3 + (size_t)sB2 * GP + base);
        uint4 vB3 = *(const uint4*)(g3 + (size_t)sB3 * GP + base);
        vA0 = selz(qA0, vA0); vA1 = selz(qA1, vA1); vA2 = selz(qA2, vA2); vA3 = selz(qA3, vA3);
        vB0 = selz(qB0, vB0); vB1 = selz(qB1, vB1); vB2 = selz(qB2, vB2); vB3 = selz(qB3, vB3);
        acc8(a, vA0); acc8(a, vA1); acc8(a, vA2); acc8(a, vA3);
        acc8(y, vB0); acc8(y, vB1); acc8(y, vB2); acc8(y, vB3);
    }
    uint4 svA = *(const uint4*)(g3 + (size_t)nA * GP + base);
    uint4 svB = *(const uint4*)(g3 + (size_t)nB * GP + base);
#pragma unroll
    for (int j = 0; j < 8; ++j) a[j] += __shfl_xor(a[j], 8);
#pragma unroll
    for (int j = 0; j < 8; ++j) a[j] += __shfl_xor(a[j], 16);
#pragma unroll
    for (int j = 0; j < 8; ++j) a[j] += __shfl_xor(a[j], 32);
#pragma unroll
    for (int j = 0; j < 8; ++j) y[j] += __shfl_xor(y[j], 8);
#pragma unroll
    for (int j = 0; j < 8; ++j) y[j] += __shfl_xor(y[j], 16);
#pragma unroll
    for (int j = 0; j < 8; ++j) y[j] += __shfl_xor(y[j], 32);
    acc8(a, svA);
    acc8(y, svB);
    float2 dv2 = *(const float2*)(dinv + nA);
    float dv = (gsl == 0) ? dv2.x : dv2.y;
    float s[8];
#pragma unroll
    for (int j = 0; j < 8; ++j) s[j] = (gsl == 0) ? a[j] : y[j];
    float z[8];
    if (c < 5) {
        float4 bb0 = *(const float4*)(b3 + base);
        float4 bb1 = *(const float4*)(b3 + base + 4);
        z[0] = s[0] * dv + bb0.x; z[1] = s[1] * dv + bb0.y;
        z[2] = s[2] * dv + bb0.z; z[3] = s[3] * dv + bb0.w;
        z[4] = s[4] * dv + bb1.x; z[5] = s[5] * dv + bb1.y;
        z[6] = s[6] * dv + bb1.z; z[7] = s[7] * dv + bb1.w;
    } else {
#pragma unroll
        for (int j = 0; j < 8; ++j) z[j] = -1e30f;
    }
    float m = fmaxf(fmaxf(fmaxf(z[0], z[1]), fmaxf(z[2], z[3])),
                    fmaxf(fmaxf(z[4], z[5]), fmaxf(z[6], z[7])));
    m = fmaxf(m, __shfl_xor(m, 1));
    m = fmaxf(m, __shfl_xor(m, 2));
    m = fmaxf(m, __shfl_xor(m, 4));
    float e = 0.f;
    if (c < 5) {
#pragma unroll
        for (int j = 0; j < 8; ++j) e += __expf(z[j] - m);
    }
    e += __shfl_xor(e, 1);
    e += __shfl_xor(e, 2);
    e += __shfl_xor(e, 4);
    float ls = __logf(e);
    if (gsl < 2 && c < 5) {
        float4 o0 = { z[0] - m - ls, z[1] - m - ls, z[2] - m - ls, z[3] - m - ls };
        float4 o1 = { z[4] - m - ls, z[5] - m - ls, z[6] - m - ls, z[7] - m - ls };
        float* orow = out + (size_t)(nA + gsl) * CD + base;
        *(float4*)(orow)     = o0;
        *(float4*)(orow + 4) = o1;
    }
}

// ---------------- launcher ----------------

extern "C" void kernel_launch(void* const* d_in, const int* in_sizes, int n_in,
                              void* d_out, int out_size, void* d_ws, size_t ws_size,
                              hipStream_t stream) {
    (void)n_in; (void)out_size; (void)ws_size;
    const float* x   = (const float*)d_in[0];
    const int*   ei  = (const int*)d_in[1];
    const float* W1  = (const float*)d_in[2];
    const float* b1  = (const float*)d_in[3];
    const float* W2  = (const float*)d_in[4];
    const float* b2  = (const float*)d_in[5];
    const float* W3  = (const float*)d_in[6];
    const float* b3  = (const float*)d_in[7];
    const float* g1  = (const float*)d_in[8];
    const float* bt1 = (const float*)d_in[9];
    const float* rm1 = (const float*)d_in[10];
    const float* rv1 = (const float*)d_in[11];
    const float* g2  = (const float*)d_in[12];
    const float* bt2 = (const float*)d_in[13];
    const float* rm2 = (const float*)d_in[14];
    const float* rv2 = (const float*)d_in[15];
    float* out = (float*)d_out;
    const int E = in_sizes[1] / 2;

    char* w = (char*)d_ws;
    auto alloc = [&](size_t bytes) { char* p = w; w += (bytes + 511) & ~(size_t)511; return p; };
    int*    bcount   = (int*)alloc((size_t)NB * 4);
    int*    bstart   = (int*)alloc((size_t)(NB + 1) * 4);
    int*    bcursor  = (int*)alloc((size_t)NB * 4);
    int*    rowstart = (int*)alloc((size_t)(NN + 1) * 4);
    float*  dinv     = (float*)alloc((size_t)NN * 4);
    int*    csr      = (int*)alloc((size_t)E * 4);
    int*    ebuf     = (int*)alloc((size_t)E * 4);
    ushort* w1t      = (ushort*)alloc((size_t)H1D * FIN * 2);
    ushort* t1       = (ushort*)alloc((size_t)NN * H1D * 2);
    ushort* t2       = (ushort*)alloc((size_t)NN * H1D * 2);
    ushort* g3       = (ushort*)alloc((size_t)NN * GP * 2);

    const int aggblocks = ((NN / 2) + 3) / 4;   // 2 nodes/wave, 4 waves/block

    hipMemsetAsync(bcount, 0, (size_t)NB * 4, stream);
    bhist_k<<<512, 256, 0, stream>>>(ei + E, E, bcount);
    bscan_k<<<1, 256, 0, stream>>>(bcount, bstart, bcursor);
    bscatter_k<<<(E + CHUNK - 1) / CHUNK, 256, 0, stream>>>(ei, ei + E, E, bcursor, ebuf);
    bcsr_k<<<NB, 256, 0, stream>>>(ebuf, bstart, rowstart, dinv, csr, E);
    w1cvt_k<<<(FIN * H1D + 255) / 256, 256, 0, stream>>>(W1, w1t);
    gemm1_k<<<(NN + 127) / 128, 512, 0, stream>>>(x, w1t, dinv, t1);
    agg64_k<1><<<aggblocks, 256, 0, stream>>>(t1, t2, rowstart, csr, dinv, g1, bt1, rm1, rv1, b1, E);
    aggp_k<<<NN / APB, 256, 0, stream>>>(t2, W2, b2, W3, g2, bt2, rm2, rv2, rowstart, csr, dinv, g3, E);
    agg40_k<<<aggblocks, 256, 0, stream>>>(g3, b3, rowstart, csr, dinv, out, E);
}

// Round 4
// 650.814 us; speedup vs baseline: 1.1619x; 1.1619x over previous
//
#include <hip/hip_runtime.h>
#include <hip/hip_bf16.h>

#define NN 100000
#define FIN 512
#define H1D 64
#define H2D 128
#define CD 40
#define GP 64           // g3 padded row (bf16) -> one 128B line
#define BNEPS 1e-5f

#define BSHIFT 9
#define BSZ 512
#define NB 196          // ceil(NN / 512)
#define CHUNK 8192      // edges per scatter block

typedef __attribute__((ext_vector_type(8))) short bf16x8;
typedef __attribute__((ext_vector_type(4))) float f32x4;

__device__ __forceinline__ float bf2f(ushort u) {
    union { uint i; float f; } v; v.i = ((uint)u) << 16; return v.f;
}
__device__ __forceinline__ ushort f2bf(float f) {
    union { float f; uint i; } v; v.f = f;
    uint x = v.i;
    return (ushort)((x + 0x7fffu + ((x >> 16) & 1u)) >> 16);
}

// unpack 8 bf16 (one 16B row chunk) and accumulate into a[0..7]
__device__ __forceinline__ void acc8(float* a, uint4 v) {
    a[0] += bf2f((ushort)(v.x & 0xffff)); a[1] += bf2f((ushort)(v.x >> 16));
    a[2] += bf2f((ushort)(v.y & 0xffff)); a[3] += bf2f((ushort)(v.y >> 16));
    a[4] += bf2f((ushort)(v.z & 0xffff)); a[5] += bf2f((ushort)(v.z >> 16));
    a[6] += bf2f((ushort)(v.w & 0xffff)); a[7] += bf2f((ushort)(v.w >> 16));
}

__device__ __forceinline__ uint4 selz(bool q, uint4 v) {
    return q ? v : make_uint4(0u, 0u, 0u, 0u);
}

// ---------------- graph preprocessing: bucketed CSR build ----------------

__global__ __launch_bounds__(256) void bhist_k(const int* __restrict__ dst, int E,
                                               int* __restrict__ bcount) {
    __shared__ int h[NB];
    for (int i = threadIdx.x; i < NB; i += 256) h[i] = 0;
    __syncthreads();
    int i = blockIdx.x * blockDim.x + threadIdx.x;
    int st = gridDim.x * blockDim.x;
    for (; i < E; i += st) atomicAdd(&h[dst[i] >> BSHIFT], 1);
    __syncthreads();
    for (int j = threadIdx.x; j < NB; j += 256)
        if (h[j]) atomicAdd(&bcount[j], h[j]);
}

__global__ __launch_bounds__(256) void bscan_k(const int* __restrict__ bcount,
                                               int* __restrict__ bstart,
                                               int* __restrict__ bcursor) {
    __shared__ int sh[NB];
    int tid = threadIdx.x;
    if (tid < NB) sh[tid] = bcount[tid];
    __syncthreads();
    for (int off = 1; off < NB; off <<= 1) {
        int v = (tid < NB && tid >= off) ? sh[tid - off] : 0;
        __syncthreads();
        if (tid < NB) sh[tid] += v;
        __syncthreads();
    }
    if (tid < NB) {
        int s = tid ? sh[tid - 1] : 0;
        bstart[tid] = s;
        bcursor[tid] = s;
    }
    if (tid == 0) bstart[NB] = sh[NB - 1];
}

__global__ __launch_bounds__(256) void bscatter_k(const int* __restrict__ src,
                                                  const int* __restrict__ dst, int E,
                                                  int* __restrict__ bcursor,
                                                  int* __restrict__ ebuf) {
    __shared__ int hist[NB];
    __shared__ int loff[NB];
    __shared__ int lcur[NB];
    __shared__ int gbase[NB];
    __shared__ int sbuf[CHUNK];
    int tid = threadIdx.x;
    int e0 = blockIdx.x * CHUNK;
    int e1 = e0 + CHUNK; if (e1 > E) e1 = E;

    for (int i = tid; i < NB; i += 256) hist[i] = 0;
    __syncthreads();
    for (int i = e0 + tid; i < e1; i += 256) atomicAdd(&hist[dst[i] >> BSHIFT], 1);
    __syncthreads();
    int v = (tid < NB) ? hist[tid] : 0;
    __syncthreads();
    if (tid < NB) loff[tid] = v;
    __syncthreads();
    for (int off = 1; off < NB; off <<= 1) {
        int u = (tid < NB && tid >= off) ? loff[tid - off] : 0;
        __syncthreads();
        if (tid < NB) loff[tid] += u;
        __syncthreads();
    }
    if (tid < NB) {
        int excl = loff[tid] - v;
        loff[tid] = excl;
        lcur[tid] = excl;
        gbase[tid] = (v > 0) ? atomicAdd(&bcursor[tid], v) : 0;
    }
    __syncthreads();
    for (int i = e0 + tid; i < e1; i += 256) {
        int d = dst[i];
        int b = d >> BSHIFT;
        int pos = atomicAdd(&lcur[b], 1);
        sbuf[pos] = (src[i] << BSHIFT) | (d & (BSZ - 1));
    }
    __syncthreads();
    int wave = tid >> 6, lane = tid & 63;
    for (int b = wave; b < NB; b += 4) {
        int cnt = (b + 1 < NB ? loff[b + 1] : (e1 - e0)) - loff[b];
        int s0 = loff[b], d0 = gbase[b];
        for (int k = lane; k < cnt; k += 64) ebuf[d0 + k] = sbuf[s0 + k];
    }
}

__global__ __launch_bounds__(256) void bcsr_k(const int* __restrict__ ebuf,
                                              const int* __restrict__ bstart,
                                              int* __restrict__ rowstart,
                                              float* __restrict__ dinv,
                                              int* __restrict__ csr, int E) {
    __shared__ int ldeg[BSZ];
    __shared__ int lcur[BSZ];
    __shared__ int s2[256];
    int b = blockIdx.x, tid = threadIdx.x;
    int node0 = b << BSHIFT;
    int es = bstart[b], ee = bstart[b + 1];
    ldeg[tid] = 0; ldeg[tid + 256] = 0;
    __syncthreads();
    for (int i = es + tid; i < ee; i += 256) atomicAdd(&ldeg[ebuf[i] & (BSZ - 1)], 1);
    __syncthreads();
    int a0 = ldeg[2 * tid], a1 = ldeg[2 * tid + 1];
    s2[tid] = a0 + a1;
    __syncthreads();
    for (int off = 1; off < 256; off <<= 1) {
        int u = (tid >= off) ? s2[tid - off] : 0;
        __syncthreads();
        s2[tid] += u;
        __syncthreads();
    }
    int base2 = tid ? s2[tid - 1] : 0;
    int ex0 = base2, ex1 = base2 + a0;
    int n0 = node0 + 2 * tid, n1 = n0 + 1;
    if (n0 < NN) { rowstart[n0] = es + ex0; dinv[n0] = rsqrtf((float)(a0 + 1)); }
    if (n1 < NN) { rowstart[n1] = es + ex1; dinv[n1] = rsqrtf((float)(a1 + 1)); }
    lcur[2 * tid] = es + ex0;
    lcur[2 * tid + 1] = es + ex1;
    __syncthreads();
    for (int i = es + tid; i < ee; i += 256) {
        int e = ebuf[i];
        int pos = atomicAdd(&lcur[e & (BSZ - 1)], 1);
        csr[pos] = ((unsigned)e) >> BSHIFT;
    }
    if (b == 0 && tid == 0) rowstart[NN] = E;
}

// ---------------- W1 -> bf16 transposed [64][512] ----------------
__global__ __launch_bounds__(256) void w1cvt_k(const float* __restrict__ W1,
                                               ushort* __restrict__ w1t) {
    int i = blockIdx.x * 256 + threadIdx.x;
    if (i < FIN * H1D) {
        int n = i >> 9, k = i & 511;
        w1t[i] = f2bf(W1[k * H1D + n]);
    }
}

// ---------------- GEMM1 (MFMA bf16): t1 = bf16( (x @ W1) * dinv ) ----------------
// block = 512 (8 waves, 128 rows), one shared 66.5KB B-stage -> 2 blocks/CU =
// 16 waves/CU = 4 waves/SIMD.
#define BPAD 520
__global__ __launch_bounds__(512) void gemm1_k(const float* __restrict__ x,
                                               const ushort* __restrict__ w1t,
                                               const float* __restrict__ dinv,
                                               ushort* __restrict__ t1) {
    __shared__ ushort sB[H1D * BPAD];   // 66.5 KB, row pad -> 2-way max conflicts
    int tid = threadIdx.x;
    {
        int row = tid >> 3, seg = tid & 7;   // 64 rows x 8 segs x 64 ushorts
        const uint4* srcp = (const uint4*)(w1t + row * FIN + seg * 64);
        uint4* dstp = (uint4*)(sB + row * BPAD + seg * 64);
#pragma unroll
        for (int j = 0; j < 8; ++j) dstp[j] = srcp[j];
    }
    __syncthreads();
    int wave = tid >> 6, lane = tid & 63;
    int lm = lane & 15, q = lane >> 4;
    int r0 = blockIdx.x * 128 + wave * 16;
    int mrow = r0 + lm;
    int mc = mrow < NN ? mrow : NN - 1;
    const float* ap = x + (size_t)mc * FIN + q * 8;
    const ushort* bp = sB + (size_t)lm * BPAD + q * 8;
    f32x4 acc0 = {0.f, 0.f, 0.f, 0.f}, acc1 = acc0, acc2 = acc0, acc3 = acc0;
#pragma unroll 4
    for (int kb = 0; kb < FIN; kb += 32) {
        f32x4 a01 = __builtin_nontemporal_load((const f32x4*)(ap + kb));
        f32x4 a23 = __builtin_nontemporal_load((const f32x4*)(ap + kb + 4));
        union { bf16x8 v8; __hip_bfloat162 h2[4]; } ua;
        ua.h2[0] = __float22bfloat162_rn(make_float2(a01[0], a01[1]));
        ua.h2[1] = __float22bfloat162_rn(make_float2(a01[2], a01[3]));
        ua.h2[2] = __float22bfloat162_rn(make_float2(a23[0], a23[1]));
        ua.h2[3] = __float22bfloat162_rn(make_float2(a23[2], a23[3]));
        bf16x8 b0 = *(const bf16x8*)(bp + kb);
        bf16x8 b1 = *(const bf16x8*)(bp + 16 * BPAD + kb);
        bf16x8 b2 = *(const bf16x8*)(bp + 32 * BPAD + kb);
        bf16x8 b3 = *(const bf16x8*)(bp + 48 * BPAD + kb);
        acc0 = __builtin_amdgcn_mfma_f32_16x16x32_bf16(ua.v8, b0, acc0, 0, 0, 0);
        acc1 = __builtin_amdgcn_mfma_f32_16x16x32_bf16(ua.v8, b1, acc1, 0, 0, 0);
        acc2 = __builtin_amdgcn_mfma_f32_16x16x32_bf16(ua.v8, b2, acc2, 0, 0, 0);
        acc3 = __builtin_amdgcn_mfma_f32_16x16x32_bf16(ua.v8, b3, acc3, 0, 0, 0);
    }
    // C/D: col = lane&15, row = q*4 + reg
    int rbase = r0 + q * 4;
#pragma unroll
    for (int r = 0; r < 4; ++r) {
        int row = rbase + r;
        if (row < NN) {
            float dv = dinv[row];
            ushort* o = t1 + (size_t)row * H1D;
            o[lm]      = f2bf(acc0[r] * dv);
            o[16 + lm] = f2bf(acc1[r] * dv);
            o[32 + lm] = f2bf(acc2[r] * dv);
            o[48 + lm] = f2bf(acc3[r] * dv);
        }
    }
}

// ---------------- aggregation over 64-dim bf16 rows, TWO nodes per wave ----------------
// Gather kernels stay LDS-free / low-VGPR: occupancy IS the latency hiding
// (R3 lesson: 45KB LDS fusion -> 33% occupancy -> gather pass 2x slower).
// MODE 1: out = relu((dinv*sum)*sc + sv) * dinv     MODE 2: out = dinv*sum
template <int MODE>
__global__ __launch_bounds__(256) void agg64_k(const ushort* __restrict__ tin,
                                               ushort* __restrict__ tout,
                                               const int* __restrict__ rowstart,
                                               const int* __restrict__ csr,
                                               const float* __restrict__ dinv,
                                               const float* __restrict__ g,
                                               const float* __restrict__ bt,
                                               const float* __restrict__ rm,
                                               const float* __restrict__ rv,
                                               const float* __restrict__ b,
                                               int E) {
    int w = (blockIdx.x * blockDim.x + threadIdx.x) >> 6;
    int lane = threadIdx.x & 63;
    int nA = 2 * w;
    if (nA >= NN) return;
    int nB = nA + 1;                 // NN even -> always valid
    int gsl = lane >> 3, c = lane & 7;
    int base = 8 * c;
    int2 r01 = *(const int2*)(rowstart + nA);
    int reB = rowstart[nA + 2];
    int iA = r01.x, reA = r01.y;
    int iB = reA;
    int Em1 = E - 1;
    float a[8], y[8];
#pragma unroll
    for (int j = 0; j < 8; ++j) { a[j] = 0.f; y[j] = 0.f; }

    for (;;) {
        bool dA = (iA + 32 <= reA);
        bool dB = (iB + 32 <= reB);
        if (!(dA | dB)) break;
        int jA0 = dA ? iA + gsl      : Em1;
        int jA1 = dA ? iA + 8 + gsl  : Em1;
        int jA2 = dA ? iA + 16 + gsl : Em1;
        int jA3 = dA ? iA + 24 + gsl : Em1;
        int jB0 = dB ? iB + gsl      : Em1;
        int jB1 = dB ? iB + 8 + gsl  : Em1;
        int jB2 = dB ? iB + 16 + gsl : Em1;
        int jB3 = dB ? iB + 24 + gsl : Em1;
        int sA0 = csr[jA0], sA1 = csr[jA1], sA2 = csr[jA2], sA3 = csr[jA3];
        int sB0 = csr[jB0], sB1 = csr[jB1], sB2 = csr[jB2], sB3 = csr[jB3];
        uint4 vA0 = *(const uint4*)(tin + (size_t)sA0 * H1D + base);
        uint4 vA1 = *(const uint4*)(tin + (size_t)sA1 * H1D + base);
        uint4 vA2 = *(const uint4*)(tin + (size_t)sA2 * H1D + base);
        uint4 vA3 = *(const uint4*)(tin + (size_t)sA3 * H1D + base);
        uint4 vB0 = *(const uint4*)(tin + (size_t)sB0 * H1D + base);
        uint4 vB1 = *(const uint4*)(tin + (size_t)sB1 * H1D + base);
        uint4 vB2 = *(const uint4*)(tin + (size_t)sB2 * H1D + base);
        uint4 vB3 = *(const uint4*)(tin + (size_t)sB3 * H1D + base);
        vA0 = selz(dA, vA0); vA1 = selz(dA, vA1); vA2 = selz(dA, vA2); vA3 = selz(dA, vA3);
        vB0 = selz(dB, vB0); vB1 = selz(dB, vB1); vB2 = selz(dB, vB2); vB3 = selz(dB, vB3);
        acc8(a, vA0); acc8(a, vA1); acc8(a, vA2); acc8(a, vA3);
        acc8(y, vB0); acc8(y, vB1); acc8(y, vB2); acc8(y, vB3);
        iA += dA ? 32 : 0;
        iB += dB ? 32 : 0;
    }
    // masked remainder batch (<=31 edges per node), 8 gathers in flight
    {
        bool qA0 = iA + gsl < reA,      qB0 = iB + gsl < reB;
        bool qA1 = iA + 8 + gsl < reA,  qB1 = iB + 8 + gsl < reB;
        bool qA2 = iA + 16 + gsl < reA, qB2 = iB + 16 + gsl < reB;
        bool qA3 = iA + 24 + gsl < reA, qB3 = iB + 24 + gsl < reB;
        int jA0 = qA0 ? iA + gsl      : Em1;
        int jA1 = qA1 ? iA + 8 + gsl  : Em1;
        int jA2 = qA2 ? iA + 16 + gsl : Em1;
        int jA3 = qA3 ? iA + 24 + gsl : Em1;
        int jB0 = qB0 ? iB + gsl      : Em1;
        int jB1 = qB1 ? iB + 8 + gsl  : Em1;
        int jB2 = qB2 ? iB + 16 + gsl : Em1;
        int jB3 = qB3 ? iB + 24 + gsl : Em1;
        int sA0 = csr[jA0], sA1 = csr[jA1], sA2 = csr[jA2], sA3 = csr[jA3];
        int sB0 = csr[jB0], sB1 = csr[jB1], sB2 = csr[jB2], sB3 = csr[jB3];
        uint4 vA0 = *(const uint4*)(tin + (size_t)sA0 * H1D + base);
        uint4 vA1 = *(const uint4*)(tin + (size_t)sA1 * H1D + base);
        uint4 vA2 = *(const uint4*)(tin + (size_t)sA2 * H1D + base);
        uint4 vA3 = *(const uint4*)(tin + (size_t)sA3 * H1D + base);
        uint4 vB0 = *(const uint4*)(tin + (size_t)sB0 * H1D + base);
        uint4 vB1 = *(const uint4*)(tin + (size_t)sB1 * H1D + base);
        uint4 vB2 = *(const uint4*)(tin + (size_t)sB2 * H1D + base);
        uint4 vB3 = *(const uint4*)(tin + (size_t)sB3 * H1D + base);
        vA0 = selz(qA0, vA0); vA1 = selz(qA1, vA1); vA2 = selz(qA2, vA2); vA3 = selz(qA3, vA3);
        vB0 = selz(qB0, vB0); vB1 = selz(qB1, vB1); vB2 = selz(qB2, vB2); vB3 = selz(qB3, vB3);
        acc8(a, vA0); acc8(a, vA1); acc8(a, vA2); acc8(a, vA3);
        acc8(y, vB0); acc8(y, vB1); acc8(y, vB2); acc8(y, vB3);
    }
    // self rows
    uint4 svA = *(const uint4*)(tin + (size_t)nA * H1D + base);
    uint4 svB = *(const uint4*)(tin + (size_t)nB * H1D + base);
#pragma unroll
    for (int j = 0; j < 8; ++j) a[j] += __shfl_xor(a[j], 8);
#pragma unroll
    for (int j = 0; j < 8; ++j) a[j] += __shfl_xor(a[j], 16);
#pragma unroll
    for (int j = 0; j < 8; ++j) a[j] += __shfl_xor(a[j], 32);
#pragma unroll
    for (int j = 0; j < 8; ++j) y[j] += __shfl_xor(y[j], 8);
#pragma unroll
    for (int j = 0; j < 8; ++j) y[j] += __shfl_xor(y[j], 16);
#pragma unroll
    for (int j = 0; j < 8; ++j) y[j] += __shfl_xor(y[j], 32);
    acc8(a, svA);
    acc8(y, svB);
    float2 dv2 = *(const float2*)(dinv + nA);
    float dv = (gsl == 0) ? dv2.x : dv2.y;
    float s[8];
#pragma unroll
    for (int j = 0; j < 8; ++j) s[j] = (gsl == 0) ? a[j] : y[j];
    float z[8];
    if (MODE == 1) {
        int f0 = base;
        float4 G0 = *(const float4*)(g + f0),  G1 = *(const float4*)(g + f0 + 4);
        float4 V0 = *(const float4*)(rv + f0), V1 = *(const float4*)(rv + f0 + 4);
        float4 B0 = *(const float4*)(b + f0),  B1 = *(const float4*)(b + f0 + 4);
        float4 M0 = *(const float4*)(rm + f0), M1 = *(const float4*)(rm + f0 + 4);
        float4 T0 = *(const float4*)(bt + f0), T1 = *(const float4*)(bt + f0 + 4);
        float sc[8] = { G0.x * rsqrtf(V0.x + BNEPS), G0.y * rsqrtf(V0.y + BNEPS),
                        G0.z * rsqrtf(V0.z + BNEPS), G0.w * rsqrtf(V0.w + BNEPS),
                        G1.x * rsqrtf(V1.x + BNEPS), G1.y * rsqrtf(V1.y + BNEPS),
                        G1.z * rsqrtf(V1.z + BNEPS), G1.w * rsqrtf(V1.w + BNEPS) };
        float sh[8] = { (B0.x - M0.x) * sc[0] + T0.x, (B0.y - M0.y) * sc[1] + T0.y,
                        (B0.z - M0.z) * sc[2] + T0.z, (B0.w - M0.w) * sc[3] + T0.w,
                        (B1.x - M1.x) * sc[4] + T1.x, (B1.y - M1.y) * sc[5] + T1.y,
                        (B1.z - M1.z) * sc[6] + T1.z, (B1.w - M1.w) * sc[7] + T1.w };
#pragma unroll
        for (int j = 0; j < 8; ++j)
            z[j] = fmaxf(s[j] * dv * sc[j] + sh[j], 0.f) * dv;
    } else {
#pragma unroll
        for (int j = 0; j < 8; ++j) z[j] = s[j] * dv;
    }
    if (gsl < 2) {
        uint4 o;
        o.x = (uint)f2bf(z[0]) | ((uint)f2bf(z[1]) << 16);
        o.y = (uint)f2bf(z[2]) | ((uint)f2bf(z[3]) << 16);
        o.z = (uint)f2bf(z[4]) | ((uint)f2bf(z[5]) << 16);
        o.w = (uint)f2bf(z[6]) | ((uint)f2bf(z[7]) << 16);
        *(uint4*)(tout + (size_t)(nA + gsl) * H1D + base) = o;
    }
}

// ---------------- MFMA GEMM2 + BN2 + ReLU + GEMM3 (split-bf16 = fp32 accuracy) ----------------
// 224 blocks stage weights ONCE, each wave loops 7 tiles of 16 nodes.
// W2/W3 stored as (hi,lo) split-bf16 packed in one uint: W == hi + lo to ~2^-17 rel.
// GEMM2: A(u2 bf16) @ (W2hi + W2lo) -> 2 MFMA per (cb,kb).
// GEMM3: h fp32 in LDS; A split on read: ahi@bhi + ahi@blo + alo@bhi.
#define W2S 66   // sW2p row stride (uints)
#define W3S 130  // sW3p row stride (uints)
#define HS  132  // hbuf row stride (floats)
__global__ __launch_bounds__(256) void p2p3m_k(const ushort* __restrict__ u2,
                                               const float* __restrict__ W2,
                                               const float* __restrict__ b2,
                                               const float* __restrict__ W3,
                                               const float* __restrict__ g2,
                                               const float* __restrict__ bt2,
                                               const float* __restrict__ rm2,
                                               const float* __restrict__ rv2,
                                               const float* __restrict__ dinv,
                                               ushort* __restrict__ g3) {
    __shared__ uint sW2p[H2D * W2S];        // [col][k] packed (hi | lo<<16), 33.8KB
    __shared__ uint sW3p[48 * W3S];         // [col][k] packed, cols 40..47 zero, 25KB
    __shared__ float sc2[H2D], sh2[H2D];
    __shared__ float hbuf[4][16 * HS];      // per-wave h fp32, 33.8KB
    int tid = threadIdx.x;
    for (int i = tid; i < H1D * H2D; i += 256) {      // W2 row-major [64][128]
        int k = i >> 7, col = i & 127;
        float wv = W2[i];
        ushort hi = f2bf(wv);
        ushort lo = f2bf(wv - bf2f(hi));
        sW2p[col * W2S + k] = (uint)hi | ((uint)lo << 16);
    }
    for (int i = tid; i < 8 * H2D; i += 256)          // zero pad cols 40..47
        sW3p[(40 + (i >> 7)) * W3S + (i & 127)] = 0u;
    for (int i = tid; i < H2D * CD; i += 256) {       // W3 row-major [128][40]
        int k = i / CD, o = i - k * CD;
        float wv = W3[i];
        ushort hi = f2bf(wv);
        ushort lo = f2bf(wv - bf2f(hi));
        sW3p[o * W3S + k] = (uint)hi | ((uint)lo << 16);
    }
    if (tid < H2D) {
        float s = g2[tid] * rsqrtf(rv2[tid] + BNEPS);
        sc2[tid] = s;
        sh2[tid] = (b2[tid] - rm2[tid]) * s + bt2[tid];
    }
    __syncthreads();
    int wave = tid >> 6, lane = tid & 63;
    int lm = lane & 15, q = lane >> 4;
    float* hb = hbuf[wave];
    for (int t = 0; t < 7; ++t) {
        int tile = blockIdx.x * 28 + wave * 7 + t;
        int r0 = tile * 16;
        if (r0 >= NN) break;
        int mrow = r0 + lm;
        int mc = mrow < NN ? mrow : NN - 1;
        bf16x8 a0 = *(const bf16x8*)(u2 + (size_t)mc * H1D + q * 8);
        bf16x8 a1 = *(const bf16x8*)(u2 + (size_t)mc * H1D + 32 + q * 8);
        // GEMM2: 8 col-blocks x {kb=0,32} x {hi,lo}
#pragma unroll
        for (int cb = 0; cb < 8; ++cb) {
            int col = cb * 16 + lm;
            const uint* wp = sW2p + col * W2S + q * 8;
            f32x4 acc = {0.f, 0.f, 0.f, 0.f};
#pragma unroll
            for (int kb = 0; kb < 2; ++kb) {
                const uint* w = wp + kb * 32;
                union { bf16x8 v; uint u[4]; } bh, bl;
#pragma unroll
                for (int p = 0; p < 4; ++p) {
                    uint w0 = w[2 * p], w1 = w[2 * p + 1];
                    bh.u[p] = (w0 & 0xffffu) | (w1 << 16);
                    bl.u[p] = (w0 >> 16) | (w1 & 0xffff0000u);
                }
                bf16x8 av = (kb == 0) ? a0 : a1;
                acc = __builtin_amdgcn_mfma_f32_16x16x32_bf16(av, bh.v, acc, 0, 0, 0);
                acc = __builtin_amdgcn_mfma_f32_16x16x32_bf16(av, bl.v, acc, 0, 0, 0);
            }
            float scv = sc2[col], shv = sh2[col];
#pragma unroll
            for (int r = 0; r < 4; ++r)
                hb[(q * 4 + r) * HS + col] = fmaxf(acc[r] * scv + shv, 0.f);
        }
        // GEMM3: D3 = (h) @ (W3hi+W3lo), h split to hi+lo on read.
        // Intra-wave LDS write->read: compiler lgkmcnt ordering suffices (per-wave buf).
        f32x4 g0 = {0.f, 0.f, 0.f, 0.f}, g1v = g0, g2v = g0;
#pragma unroll
        for (int kb = 0; kb < 4; ++kb) {
            const float* hp = hb + lm * HS + kb * 32 + q * 8;
            union { bf16x8 v; uint u[4]; } ah, al;
#pragma unroll
            for (int p = 0; p < 2; ++p) {
                float4 h4 = *(const float4*)(hp + 4 * p);
                ushort h0 = f2bf(h4.x), h1 = f2bf(h4.y), h2 = f2bf(h4.z), h3 = f2bf(h4.w);
                ah.u[2 * p]     = (uint)h0 | ((uint)h1 << 16);
                ah.u[2 * p + 1] = (uint)h2 | ((uint)h3 << 16);
                ushort l0 = f2bf(h4.x - bf2f(h0)), l1 = f2bf(h4.y - bf2f(h1));
                ushort l2 = f2bf(h4.z - bf2f(h2)), l3 = f2bf(h4.w - bf2f(h3));
                al.u[2 * p]     = (uint)l0 | ((uint)l1 << 16);
                al.u[2 * p + 1] = (uint)l2 | ((uint)l3 << 16);
            }
#pragma unroll
            for (int cb = 0; cb < 3; ++cb) {
                const uint* w = sW3p + (cb * 16 + lm) * W3S + kb * 32 + q * 8;
                union { bf16x8 v; uint u[4]; } bh, bl;
#pragma unroll
                for (int p = 0; p < 4; ++p) {
                    uint w0 = w[2 * p], w1 = w[2 * p + 1];
                    bh.u[p] = (w0 & 0xffffu) | (w1 << 16);
                    bl.u[p] = (w0 >> 16) | (w1 & 0xffff0000u);
                }
                f32x4 acc = (cb == 0) ? g0 : (cb == 1) ? g1v : g2v;
                acc = __builtin_amdgcn_mfma_f32_16x16x32_bf16(ah.v, bh.v, acc, 0, 0, 0);
                acc = __builtin_amdgcn_mfma_f32_16x16x32_bf16(ah.v, bl.v, acc, 0, 0, 0);
                acc = __builtin_amdgcn_mfma_f32_16x16x32_bf16(al.v, bh.v, acc, 0, 0, 0);
                if (cb == 0) g0 = acc; else if (cb == 1) g1v = acc; else g2v = acc;
            }
        }
        // store: D3[row=q*4+r][col=cb*16+lm], col<40 valid; *dinv -> g3 (bf16, GP pad)
#pragma unroll
        for (int r = 0; r < 4; ++r) {
            int row = r0 + q * 4 + r;
            if (row < NN) {
                float dv = dinv[row];
                ushort* op = g3 + (size_t)row * GP;
                op[lm]      = f2bf(g0[r] * dv);
                op[16 + lm] = f2bf(g1v[r] * dv);
                if (lm < 8) op[32 + lm] = f2bf(g2v[r] * dv);
            }
        }
    }
}

// ---------------- aggregation over padded 40-dim bf16 + bias + log_softmax ----------------
__global__ __launch_bounds__(256) void agg40_k(const ushort* __restrict__ g3,
                                               const float* __restrict__ b3,
                                               const int* __restrict__ rowstart,
                                               const int* __restrict__ csr,
                                               const float* __restrict__ dinv,
                                               float* __restrict__ out,
                                               int E) {
    int w = (blockIdx.x * blockDim.x + threadIdx.x) >> 6;
    int lane = threadIdx.x & 63;
    int nA = 2 * w;
    if (nA >= NN) return;
    int nB = nA + 1;
    int gsl = lane >> 3, c = lane & 7;
    int base = 8 * c;
    int2 r01 = *(const int2*)(rowstart + nA);
    int reB = rowstart[nA + 2];
    int iA = r01.x, reA = r01.y;
    int iB = reA;
    int Em1 = E - 1;
    float a[8], y[8];
#pragma unroll
    for (int j = 0; j < 8; ++j) { a[j] = 0.f; y[j] = 0.f; }

    for (;;) {
        bool dA = (iA + 32 <= reA);
        bool dB = (iB + 32 <= reB);
        if (!(dA | dB)) break;
        int jA0 = dA ? iA + gsl      : Em1;
        int jA1 = dA ? iA + 8 + gsl  : Em1;
        int jA2 = dA ? iA + 16 + gsl : Em1;
        int jA3 = dA ? iA + 24 + gsl : Em1;
        int jB0 = dB ? iB + gsl      : Em1;
        int jB1 = dB ? iB + 8 + gsl  : Em1;
        int jB2 = dB ? iB + 16 + gsl : Em1;
        int jB3 = dB ? iB + 24 + gsl : Em1;
        int sA0 = csr[jA0], sA1 = csr[jA1], sA2 = csr[jA2], sA3 = csr[jA3];
        int sB0 = csr[jB0], sB1 = csr[jB1], sB2 = csr[jB2], sB3 = csr[jB3];
        uint4 vA0 = *(const uint4*)(g3 + (size_t)sA0 * GP + base);
        uint4 vA1 = *(const uint4*)(g3 + (size_t)sA1 * GP + base);
        uint4 vA2 = *(const uint4*)(g3 + (size_t)sA2 * GP + base);
        uint4 vA3 = *(const uint4*)(g3 + (size_t)sA3 * GP + base);
        uint4 vB0 = *(const uint4*)(g3 + (size_t)sB0 * GP + base);
        uint4 vB1 = *(const uint4*)(g3 + (size_t)sB1 * GP + base);
        uint4 vB2 = *(const uint4*)(g3 + (size_t)sB2 * GP + base);
        uint4 vB3 = *(const uint4*)(g3 + (size_t)sB3 * GP + base);
        vA0 = selz(dA, vA0); vA1 = selz(dA, vA1); vA2 = selz(dA, vA2); vA3 = selz(dA, vA3);
        vB0 = selz(dB, vB0); vB1 = selz(dB, vB1); vB2 = selz(dB, vB2); vB3 = selz(dB, vB3);
        acc8(a, vA0); acc8(a, vA1); acc8(a, vA2); acc8(a, vA3);
        acc8(y, vB0); acc8(y, vB1); acc8(y, vB2); acc8(y, vB3);
        iA += dA ? 32 : 0;
        iB += dB ? 32 : 0;
    }
    {
        bool qA0 = iA + gsl < reA,      qB0 = iB + gsl < reB;
        bool qA1 = iA + 8 + gsl < reA,  qB1 = iB + 8 + gsl < reB;
        bool qA2 = iA + 16 + gsl < reA, qB2 = iB + 16 + gsl < reB;
        bool qA3 = iA + 24 + gsl < reA, qB3 = iB + 24 + gsl < reB;
        int jA0 = qA0 ? iA + gsl      : Em1;
        int jA1 = qA1 ? iA + 8 + gsl  : Em1;
        int jA2 = qA2 ? iA + 16 + gsl : Em1;
        int jA3 = qA3 ? iA + 24 + gsl : Em1;
        int jB0 = qB0 ? iB + gsl      : Em1;
        int jB1 = qB1 ? iB + 8 + gsl  : Em1;
        int jB2 = qB2 ? iB + 16 + gsl : Em1;
        int jB3 = qB3 ? iB + 24 + gsl : Em1;
        int sA0 = csr[jA0], sA1 = csr[jA1], sA2 = csr[jA2], sA3 = csr[jA3];
        int sB0 = csr[jB0], sB1 = csr[jB1], sB2 = csr[jB2], sB3 = csr[jB3];
        uint4 vA0 = *(const uint4*)(g3 + (size_t)sA0 * GP + base);
        uint4 vA1 = *(const uint4*)(g3 + (size_t)sA1 * GP + base);
        uint4 vA2 = *(const uint4*)(g3 + (size_t)sA2 * GP + base);
        uint4 vA3 = *(const uint4*)(g3 + (size_t)sA3 * GP + base);
        uint4 vB0 = *(const uint4*)(g3 + (size_t)sB0 * GP + base);
        uint4 vB1 = *(const uint4*)(g3 + (size_t)sB1 * GP + base);
        uint4 vB2 = *(const uint4*)(g3 + (size_t)sB2 * GP + base);
        uint4 vB3 = *(const uint4*)(g3 + (size_t)sB3 * GP + base);
        vA0 = selz(qA0, vA0); vA1 = selz(qA1, vA1); vA2 = selz(qA2, vA2); vA3 = selz(qA3, vA3);
        vB0 = selz(qB0, vB0); vB1 = selz(qB1, vB1); vB2 = selz(qB2, vB2); vB3 = selz(qB3, vB3);
        acc8(a, vA0); acc8(a, vA1); acc8(a, vA2); acc8(a, vA3);
        acc8(y, vB0); acc8(y, vB1); acc8(y, vB2); acc8(y, vB3);
    }
    uint4 svA = *(const uint4*)(g3 + (size_t)nA * GP + base);
    uint4 svB = *(const uint4*)(g3 + (size_t)nB * GP + base);
#pragma unroll
    for (int j = 0; j < 8; ++j) a[j] += __shfl_xor(a[j], 8);
#pragma unroll
    for (int j = 0; j < 8; ++j) a[j] += __shfl_xor(a[j], 16);
#pragma unroll
    for (int j = 0; j < 8; ++j) a[j] += __shfl_xor(a[j], 32);
#pragma unroll
    for (int j = 0; j < 8; ++j) y[j] += __shfl_xor(y[j], 8);
#pragma unroll
    for (int j = 0; j < 8; ++j) y[j] += __shfl_xor(y[j], 16);
#pragma unroll
    for (int j = 0; j < 8; ++j) y[j] += __shfl_xor(y[j], 32);
    acc8(a, svA);
    acc8(y, svB);
    float2 dv2 = *(const float2*)(dinv + nA);
    float dv = (gsl == 0) ? dv2.x : dv2.y;
    float s[8];
#pragma unroll
    for (int j = 0; j < 8; ++j) s[j] = (gsl == 0) ? a[j] : y[j];
    float z[8];
    if (c < 5) {
        float4 bb0 = *(const float4*)(b3 + base);
        float4 bb1 = *(const float4*)(b3 + base + 4);
        z[0] = s[0] * dv + bb0.x; z[1] = s[1] * dv + bb0.y;
        z[2] = s[2] * dv + bb0.z; z[3] = s[3] * dv + bb0.w;
        z[4] = s[4] * dv + bb1.x; z[5] = s[5] * dv + bb1.y;
        z[6] = s[6] * dv + bb1.z; z[7] = s[7] * dv + bb1.w;
    } else {
#pragma unroll
        for (int j = 0; j < 8; ++j) z[j] = -1e30f;
    }
    float m = fmaxf(fmaxf(fmaxf(z[0], z[1]), fmaxf(z[2], z[3])),
                    fmaxf(fmaxf(z[4], z[5]), fmaxf(z[6], z[7])));
    m = fmaxf(m, __shfl_xor(m, 1));
    m = fmaxf(m, __shfl_xor(m, 2));
    m = fmaxf(m, __shfl_xor(m, 4));
    float e = 0.f;
    if (c < 5) {
#pragma unroll
        for (int j = 0; j < 8; ++j) e += __expf(z[j] - m);
    }
    e += __shfl_xor(e, 1);
    e += __shfl_xor(e, 2);
    e += __shfl_xor(e, 4);
    float ls = __logf(e);
    if (gsl < 2 && c < 5) {
        float4 o0 = { z[0] - m - ls, z[1] - m - ls, z[2] - m - ls, z[3] - m - ls };
        float4 o1 = { z[4] - m - ls, z[5] - m - ls, z[6] - m - ls, z[7] - m - ls };
        float* orow = out + (size_t)(nA + gsl) * CD + base;
        *(float4*)(orow)     = o0;
        *(float4*)(orow + 4) = o1;
    }
}

// ---------------- launcher ----------------

extern "C" void kernel_launch(void* const* d_in, const int* in_sizes, int n_in,
                              void* d_out, int out_size, void* d_ws, size_t ws_size,
                              hipStream_t stream) {
    (void)n_in; (void)out_size; (void)ws_size;
    const float* x   = (const float*)d_in[0];
    const int*   ei  = (const int*)d_in[1];
    const float* W1  = (const float*)d_in[2];
    const float* b1  = (const float*)d_in[3];
    const float* W2  = (const float*)d_in[4];
    const float* b2  = (const float*)d_in[5];
    const float* W3  = (const float*)d_in[6];
    const float* b3  = (const float*)d_in[7];
    const float* g1  = (const float*)d_in[8];
    const float* bt1 = (const float*)d_in[9];
    const float* rm1 = (const float*)d_in[10];
    const float* rv1 = (const float*)d_in[11];
    const float* g2  = (const float*)d_in[12];
    const float* bt2 = (const float*)d_in[13];
    const float* rm2 = (const float*)d_in[14];
    const float* rv2 = (const float*)d_in[15];
    float* out = (float*)d_out;
    const int E = in_sizes[1] / 2;

    char* w = (char*)d_ws;
    auto alloc = [&](size_t bytes) { char* p = w; w += (bytes + 511) & ~(size_t)511; return p; };
    int*    bcount   = (int*)alloc((size_t)NB * 4);
    int*    bstart   = (int*)alloc((size_t)(NB + 1) * 4);
    int*    bcursor  = (int*)alloc((size_t)NB * 4);
    int*    rowstart = (int*)alloc((size_t)(NN + 1) * 4);
    float*  dinv     = (float*)alloc((size_t)NN * 4);
    int*    csr      = (int*)alloc((size_t)E * 4);
    int*    ebuf     = (int*)alloc((size_t)E * 4);
    ushort* w1t      = (ushort*)alloc((size_t)H1D * FIN * 2);
    ushort* t1       = (ushort*)alloc((size_t)NN * H1D * 2);
    ushort* t2       = (ushort*)alloc((size_t)NN * H1D * 2);
    ushort* g3       = (ushort*)alloc((size_t)NN * GP * 2);

    const int aggblocks = ((NN / 2) + 3) / 4;   // 2 nodes/wave, 4 waves/block

    hipMemsetAsync(bcount, 0, (size_t)NB * 4, stream);
    bhist_k<<<512, 256, 0, stream>>>(ei + E, E, bcount);
    bscan_k<<<1, 256, 0, stream>>>(bcount, bstart, bcursor);
    bscatter_k<<<(E + CHUNK - 1) / CHUNK, 256, 0, stream>>>(ei, ei + E, E, bcursor, ebuf);
    bcsr_k<<<NB, 256, 0, stream>>>(ebuf, bstart, rowstart, dinv, csr, E);
    w1cvt_k<<<(FIN * H1D + 255) / 256, 256, 0, stream>>>(W1, w1t);
    gemm1_k<<<(NN + 127) / 128, 512, 0, stream>>>(x, w1t, dinv, t1);
    agg64_k<1><<<aggblocks, 256, 0, stream>>>(t1, t2, rowstart, csr, dinv, g1, bt1, rm1, rv1, b1, E);
    agg64_k<2><<<aggblocks, 256, 0, stream>>>(t2, t1, rowstart, csr, dinv, nullptr, nullptr, nullptr, nullptr, nullptr, E);
    p2p3m_k<<<224, 256, 0, stream>>>(t1, W2, b2, W3, g2, bt2, rm2, rv2, dinv, g3);
    agg40_k<<<aggblocks, 256, 0, stream>>>(g3, b3, rowstart, csr, dinv, out, E);
}